// Round 9
// baseline (2864.266 us; speedup 1.0000x reference)
//
#include <hip/hip_runtime.h>

#define N_NODES 10000
#define NEDGE 160000
#define NB 80000  /* N_NODES*BATCH */
#define GRID 1024 /* 4 blocks/CU x 256 CUs; __launch_bounds__(256,4) guarantees residency */

typedef unsigned int u32;
typedef unsigned short u16;
typedef __attribute__((ext_vector_type(8))) short short8;
typedef __attribute__((ext_vector_type(4))) float float4v;

__device__ __forceinline__ u16 f2bf(float f) {
    u32 u = __float_as_uint(f);
    return (u16)((u + 0x7fffu + ((u >> 16) & 1u)) >> 16);
}
__device__ __forceinline__ float lo16(u32 u) { return __uint_as_float(u << 16); }
__device__ __forceinline__ float hi16(u32 u) { return __uint_as_float(u & 0xffff0000u); }
__device__ __forceinline__ u32 pack2(float a, float b) {
    return (u32)f2bf(a) | (((u32)f2bf(b)) << 16);
}
__device__ __forceinline__ float fast_tanh(float v) {
    return 1.f - 2.f / (__expf(2.f * v) + 1.f);
}

// software grid barrier: device-scope counter + fences (all GRID blocks co-resident)
__device__ __forceinline__ void gbar(int* ctr, int target) {
    __syncthreads();
    if (threadIdx.x == 0) {
        __threadfence();  // release: flush this block's prior writes to coherent point
        __hip_atomic_fetch_add(ctr, 1, __ATOMIC_RELEASE, __HIP_MEMORY_SCOPE_AGENT);
        while (__hip_atomic_load(ctr, __ATOMIC_ACQUIRE, __HIP_MEMORY_SCOPE_AGENT) < target)
            __builtin_amdgcn_s_sleep(2);
        __threadfence();  // acquire: invalidate stale L1/L2 before reading others' data
    }
    __syncthreads();
}

struct MegaArgs {
    const float2* y;
    const float* W_lat;
    const float* b_lat;
    const float* W_units;
    const float* b_units;
    const float* W_final;
    const float* sup1w;
    const float* sup2w;
    const int* rows;
    const int* cols;
    float* out;
    int* rowptr1;
    int* rowptr2;
    int* cnt;
    int* bsums;
    int* barrier;
    int2* edges1;
    int2* edges2;
    u16* bpk12;
    u16* bpkP;
    u16* theta;
    u16* S;
    u16* H0;
    u16* T1;
    u16* T2;
};

static const size_t SLAB = (size_t)NB * 64;  // u16 elems per 64-wide slab

// ---------------- SpMM gather: full-width row, 4-deep MLP unroll (R6-proven) --------
__device__ __forceinline__ void gacc(float* acc, float w, uint4 u) {
    acc[0] += w * lo16(u.x); acc[1] += w * hi16(u.x);
    acc[2] += w * lo16(u.y); acc[3] += w * hi16(u.y);
    acc[4] += w * lo16(u.z); acc[5] += w * hi16(u.z);
    acc[6] += w * lo16(u.w); acc[7] += w * hi16(u.w);
}

__device__ __forceinline__ void gather_row(const u32* __restrict__ Xin,
                                           const int* __restrict__ rp,
                                           const int2* __restrict__ eg,
                                           int n, int lane, float* acc) {
    int e0 = rp[n], e1 = rp[n + 1];
    for (int base = e0; base < e1; base += 64) {
        int m = min(64, e1 - base);
        int2 me = make_int2(0, 0);
        if (lane < m) me = eg[base + lane];
        int j = 0;
        for (; j + 4 <= m; j += 4) {
            int s0 = __shfl(me.x, j, 64);
            int s1 = __shfl(me.x, j + 1, 64);
            int s2 = __shfl(me.x, j + 2, 64);
            int s3 = __shfl(me.x, j + 3, 64);
            float w0 = __int_as_float(__shfl(me.y, j, 64));
            float w1 = __int_as_float(__shfl(me.y, j + 1, 64));
            float w2 = __int_as_float(__shfl(me.y, j + 2, 64));
            float w3 = __int_as_float(__shfl(me.y, j + 3, 64));
            uint4 u0 = *(const uint4*)(Xin + (size_t)s0 * 256 + lane * 4);
            uint4 u1 = *(const uint4*)(Xin + (size_t)s1 * 256 + lane * 4);
            uint4 u2 = *(const uint4*)(Xin + (size_t)s2 * 256 + lane * 4);
            uint4 u3 = *(const uint4*)(Xin + (size_t)s3 * 256 + lane * 4);
            gacc(acc, w0, u0);
            gacc(acc, w1, u1);
            gacc(acc, w2, u2);
            gacc(acc, w3, u3);
        }
        for (; j < m; j++) {
            int src = __shfl(me.x, j, 64);
            float w = __int_as_float(__shfl(me.y, j, 64));
            uint4 u = *(const uint4*)(Xin + (size_t)src * 256 + lane * 4);
            gacc(acc, w, u);
        }
    }
}

// dual-list axpby spmm phase: 5000 virtual groups x 4 waves (1 node/wave)
__device__ void spmm_phase(const u32* __restrict__ XinA, const u32* __restrict__ XprevA,
                           u32* __restrict__ XoutA,
                           const u32* __restrict__ XinB, const u32* __restrict__ XprevB,
                           u32* __restrict__ XoutB,
                           const int* __restrict__ rp1, const int2* __restrict__ eg1,
                           const int* __restrict__ rp2, const int2* __restrict__ eg2,
                           float alpha, float beta) {
    int lane = threadIdx.x & 63;
    int wave = threadIdx.x >> 6;
    for (int g = blockIdx.x; g < 5000; g += GRID) {
        int v = g * 4 + wave;  // < 20000 always
        bool hB = v >= N_NODES;
        int n = hB ? v - N_NODES : v;
        const u32* Xin = hB ? XinB : XinA;
        const u32* Xprev = hB ? XprevB : XprevA;
        u32* Xout = hB ? XoutB : XoutA;
        const int* rp = hB ? rp2 : rp1;
        const int2* eg = hB ? eg2 : eg1;

        float acc[8] = {0.f, 0.f, 0.f, 0.f, 0.f, 0.f, 0.f, 0.f};
        gather_row(Xin, rp, eg, n, lane, acc);

        size_t o = (size_t)n * 256 + lane * 4;
        if (beta != 0.f) {
            uint4 p = *(const uint4*)(Xprev + o);
            acc[0] = alpha * acc[0] + beta * lo16(p.x); acc[1] = alpha * acc[1] + beta * hi16(p.x);
            acc[2] = alpha * acc[2] + beta * lo16(p.y); acc[3] = alpha * acc[3] + beta * hi16(p.y);
            acc[4] = alpha * acc[4] + beta * lo16(p.z); acc[5] = alpha * acc[5] + beta * hi16(p.z);
            acc[6] = alpha * acc[6] + beta * lo16(p.w); acc[7] = alpha * acc[7] + beta * hi16(p.w);
        } else {
#pragma unroll
            for (int i = 0; i < 8; i++) acc[i] *= alpha;
        }
        uint4 r;
        r.x = pack2(acc[0], acc[1]);
        r.y = pack2(acc[2], acc[3]);
        r.z = pack2(acc[4], acc[5]);
        r.w = pack2(acc[6], acc[7]);
        *(uint4*)(Xout + o) = r;
    }
}

__device__ void final_phase(const u32* __restrict__ T1, const u32* __restrict__ T2,
                            const u32* __restrict__ Q, const u32* __restrict__ theta,
                            const int* __restrict__ rp1, const int2* __restrict__ eg1,
                            const int* __restrict__ rp2, const int2* __restrict__ eg2,
                            float* __restrict__ outF) {
    int lane = threadIdx.x & 63;
    int wave = threadIdx.x >> 6;
    for (int g = blockIdx.x; g < 2500; g += GRID) {
        int n = g * 4 + wave;  // < 10000
        float acc[8] = {0.f, 0.f, 0.f, 0.f, 0.f, 0.f, 0.f, 0.f};
        gather_row(T1, rp1, eg1, n, lane, acc);
        gather_row(T2, rp2, eg2, n, lane, acc);

        size_t o = (size_t)n * 256 + lane * 4;
        uint4 q = *(const uint4*)(Q + o);
        uint4 th = *(const uint4*)(theta + o);
        float res[8];
        res[0] = -lo16(th.x) * fast_tanh(lo16(q.x) + acc[0]);
        res[1] = -hi16(th.x) * fast_tanh(hi16(q.x) + acc[1]);
        res[2] = -lo16(th.y) * fast_tanh(lo16(q.y) + acc[2]);
        res[3] = -hi16(th.y) * fast_tanh(hi16(q.y) + acc[3]);
        res[4] = -lo16(th.z) * fast_tanh(lo16(q.z) + acc[4]);
        res[5] = -hi16(th.z) * fast_tanh(hi16(q.z) + acc[5]);
        res[6] = -lo16(th.w) * fast_tanh(lo16(q.w) + acc[6]);
        res[7] = -hi16(th.w) * fast_tanh(hi16(q.w) + acc[7]);
        int b = lane >> 3;
        int f0 = ((lane * 4) & 31) * 2;
        float* dst = outF + (size_t)b * (N_NODES * 64) + (size_t)n * 64 + f0;
        *(float4*)(dst) = make_float4(res[0], res[1], res[2], res[3]);
        *(float4*)(dst + 4) = make_float4(res[4], res[5], res[6], res[7]);
    }
}

// ---------------- GEMM phases ----------------
// gemm12: A = 5 x-slabs (64-wide), K=320, NOUT=192; col<64 sigmoid->theta, else tanh->H0
__device__ void gemm12_phase(const u16* __restrict__ S, const u16* __restrict__ Bp,
                             const float* __restrict__ b_lat, const float* __restrict__ b_units,
                             u16* __restrict__ theta, u16* __restrict__ H0) {
    int lane = threadIdx.x & 63;
    int wave = threadIdx.x >> 6;
    int mrow = lane & 15;
    int kq = lane >> 4;
    for (int tile = blockIdx.x; tile < 1250; tile += GRID) {
        int rowBase = tile * 64 + wave * 16;
        float4v acc[12];
#pragma unroll
        for (int c = 0; c < 12; c++) acc[c] = (float4v){0.f, 0.f, 0.f, 0.f};
#pragma unroll
        for (int ks = 0; ks < 10; ks++) {
            int k = ks * 32 + kq * 8;
            int m = k >> 6;
            int koff = k & 63;
            short8 a = *(const short8*)(S + (size_t)m * SLAB + (size_t)(rowBase + mrow) * 64 + koff);
            const u16* bb = Bp + ((size_t)(ks * 12) * 64 + lane) * 8;
#pragma unroll
            for (int cb = 0; cb < 3; cb++) {  // batches of 4 B-tiles: caps VGPR
                short8 b0 = *(const short8*)(bb + (size_t)(cb * 4 + 0) * 512);
                short8 b1 = *(const short8*)(bb + (size_t)(cb * 4 + 1) * 512);
                short8 b2 = *(const short8*)(bb + (size_t)(cb * 4 + 2) * 512);
                short8 b3 = *(const short8*)(bb + (size_t)(cb * 4 + 3) * 512);
                acc[cb * 4 + 0] = __builtin_amdgcn_mfma_f32_16x16x32_bf16(a, b0, acc[cb * 4 + 0], 0, 0, 0);
                acc[cb * 4 + 1] = __builtin_amdgcn_mfma_f32_16x16x32_bf16(a, b1, acc[cb * 4 + 1], 0, 0, 0);
                acc[cb * 4 + 2] = __builtin_amdgcn_mfma_f32_16x16x32_bf16(a, b2, acc[cb * 4 + 2], 0, 0, 0);
                acc[cb * 4 + 3] = __builtin_amdgcn_mfma_f32_16x16x32_bf16(a, b3, acc[cb * 4 + 3], 0, 0, 0);
            }
        }
        int rowq = rowBase + kq * 4;
#pragma unroll
        for (int ct = 0; ct < 12; ct++) {
            int col = ct * 16 + mrow;
            float bsv = (col < 64) ? b_lat[col] : b_units[col - 64];
#pragma unroll
            for (int i = 0; i < 4; i++) {
                float v = acc[ct][i] + bsv;
                int r = rowq + i;
                if (col < 64) {
                    v = 1.f / (1.f + __expf(-v));
                    theta[(size_t)r * 64 + col] = f2bf(v);
                } else {
                    H0[(size_t)r * 128 + (col - 64)] = f2bf(fast_tanh(v));
                }
            }
        }
    }
}

// gemmP: A = H0 (128-wide), K=128, NOUT=320, col-split x2 -> P slabs (bias on slot0)
__device__ void gemmP_phase(const u16* __restrict__ H0, const u16* __restrict__ Bp,
                            const float* __restrict__ b_lat, u16* __restrict__ P) {
    int lane = threadIdx.x & 63;
    int wave = threadIdx.x >> 6;
    int mrow = lane & 15;
    int kq = lane >> 4;
    for (int tile = blockIdx.x; tile < 2500; tile += GRID) {
        int rowBase = (tile >> 1) * 64 + wave * 16;
        int ctBase = (tile & 1) * 10;
        float4v acc[10];
#pragma unroll
        for (int c = 0; c < 10; c++) acc[c] = (float4v){0.f, 0.f, 0.f, 0.f};
#pragma unroll
        for (int ks = 0; ks < 4; ks++) {
            int k = ks * 32 + kq * 8;
            short8 a = *(const short8*)(H0 + (size_t)(rowBase + mrow) * 128 + k);
            const u16* bb = Bp + ((size_t)(ks * 20 + ctBase) * 64 + lane) * 8;
#pragma unroll
            for (int cb = 0; cb < 2; cb++) {  // batches of 5
                short8 b0 = *(const short8*)(bb + (size_t)(cb * 5 + 0) * 512);
                short8 b1 = *(const short8*)(bb + (size_t)(cb * 5 + 1) * 512);
                short8 b2 = *(const short8*)(bb + (size_t)(cb * 5 + 2) * 512);
                short8 b3 = *(const short8*)(bb + (size_t)(cb * 5 + 3) * 512);
                short8 b4 = *(const short8*)(bb + (size_t)(cb * 5 + 4) * 512);
                acc[cb * 5 + 0] = __builtin_amdgcn_mfma_f32_16x16x32_bf16(a, b0, acc[cb * 5 + 0], 0, 0, 0);
                acc[cb * 5 + 1] = __builtin_amdgcn_mfma_f32_16x16x32_bf16(a, b1, acc[cb * 5 + 1], 0, 0, 0);
                acc[cb * 5 + 2] = __builtin_amdgcn_mfma_f32_16x16x32_bf16(a, b2, acc[cb * 5 + 2], 0, 0, 0);
                acc[cb * 5 + 3] = __builtin_amdgcn_mfma_f32_16x16x32_bf16(a, b3, acc[cb * 5 + 3], 0, 0, 0);
                acc[cb * 5 + 4] = __builtin_amdgcn_mfma_f32_16x16x32_bf16(a, b4, acc[cb * 5 + 4], 0, 0, 0);
            }
        }
        int rowq = rowBase + kq * 4;
#pragma unroll
        for (int ct = 0; ct < 10; ct++) {
            int col = (ctBase + ct) * 16 + mrow;
            float bsv = (col < 64) ? b_lat[col] : 0.f;
#pragma unroll
            for (int i = 0; i < 4; i++) {
                float v = acc[ct][i] + bsv;
                int r = rowq + i;
                P[(size_t)(col >> 6) * SLAB + (size_t)r * 64 + (col & 63)] = f2bf(v);
            }
        }
    }
}

// ---------------- mega kernel ----------------
__global__ __launch_bounds__(256, 4) void mega_kernel(MegaArgs a) {
    __shared__ int sh[256];
    int t = threadIdx.x;
    int phase = 0;

    // phase 0: transpose + bpack12 + bpackP + zero cnt
    for (int wb = blockIdx.x; wb < 10479; wb += GRID) {
        if (wb < 10000) {
            int idx = wb * 256 + t;
            int fh = idx & 31;
            int rb = idx >> 5;
            int bb = rb & 7;
            int n = rb >> 3;
            float2 v = a.y[((size_t)bb * N_NODES + n) * 32 + fh];
            ((u32*)a.S)[idx] = pack2(v.x, v.y);
        } else if (wb < 10240) {
            int idx = (wb - 10000) * 256 + t;  // < 61440
            int j = idx & 7;
            int lane = (idx >> 3) & 63;
            int rest = idx >> 9;
            int ct = rest % 12;
            int ks = rest / 12;
            int k = ks * 32 + (lane >> 4) * 8 + j;
            int col = ct * 16 + (lane & 15);
            int wrow = (k % 64) * 5 + (k / 64);
            float v = (col < 64) ? a.W_lat[wrow * 64 + col] : a.W_units[wrow * 128 + (col - 64)];
            a.bpk12[idx] = f2bf(v);
        } else if (wb < 10400) {
            int idx = (wb - 10240) * 256 + t;  // < 40960
            int j8 = idx & 7;
            int lane = (idx >> 3) & 63;
            int rest = idx >> 9;
            int ct = rest % 20;
            int ks = rest / 20;
            int k = ks * 32 + (lane >> 4) * 8 + j8;
            int col = ct * 16 + (lane & 15);
            int slot = col >> 6, j = col & 63;
            float v;
            if (slot == 0)
                v = a.W_final[(k * 5 + 0) * 64 + j] - a.W_final[(k * 5 + 2) * 64 + j] -
                    a.W_final[(k * 5 + 4) * 64 + j];
            else
                v = a.W_final[(k * 5 + slot) * 64 + j];
            a.bpkP[idx] = f2bf(v);
        } else {
            int idx = (wb - 10400) * 256 + t;
            if (idx < 2 * N_NODES) a.cnt[idx] = 0;
        }
    }
    gbar(a.barrier, ++phase * GRID);

    // phase 1: count (625 * 256 == NEDGE exactly)
    for (int wb = blockIdx.x; wb < 625; wb += GRID) {
        int e = wb * 256 + t;
        atomicAdd(&a.cnt[a.cols[e]], 1);            // support1: dst=cols
        atomicAdd(&a.cnt[N_NODES + a.rows[e]], 1);  // support2: dst=rows
    }
    gbar(a.barrier, ++phase * GRID);

    // phase 2: per-chunk block sums (80 chunks: arr*40 + c)
    for (int wb = blockIdx.x; wb < 80; wb += GRID) {
        int arr = wb / 40, c = wb % 40;
        int idx = c * 256 + t;
        int v = (idx < N_NODES) ? a.cnt[arr * N_NODES + idx] : 0;
#pragma unroll
        for (int off = 32; off; off >>= 1) v += __shfl_down(v, off, 64);
        int wv = t >> 6, ln = t & 63;
        if (ln == 0) sh[wv] = v;
        __syncthreads();
        if (t == 0) a.bsums[wb] = sh[0] + sh[1] + sh[2] + sh[3];
        __syncthreads();
    }
    gbar(a.barrier, ++phase * GRID);

    // phase 3: scanapply with inlined serial mid-scan of the 40 partials per array
    for (int wb = blockIdx.x; wb < 80; wb += GRID) {
        int arr = wb / 40, c = wb % 40;
        int base = 0;
        for (int i = 0; i < c; i++) base += a.bsums[arr * 40 + i];
        int idx = c * 256 + t;
        bool ok = idx < N_NODES;
        int v = ok ? a.cnt[arr * N_NODES + idx] : 0;
        sh[t] = v;
        __syncthreads();
        for (int off = 1; off < 256; off <<= 1) {
            int add = (t >= off) ? sh[t - off] : 0;
            __syncthreads();
            sh[t] += add;
            __syncthreads();
        }
        int excl = sh[t] - v + base;
        if (ok) {
            int* rp = arr ? a.rowptr2 : a.rowptr1;
            rp[idx] = excl;
            a.cnt[arr * N_NODES + idx] = excl;  // cursor
        }
        __syncthreads();
    }
    if (blockIdx.x == 0 && t == 0) {
        a.rowptr1[N_NODES] = NEDGE;
        a.rowptr2[N_NODES] = NEDGE;
    }
    gbar(a.barrier, ++phase * GRID);

    // phase 4: scatter
    for (int wb = blockIdx.x; wb < 625; wb += GRID) {
        int e = wb * 256 + t;
        int r = a.rows[e], c = a.cols[e];
        int p1 = atomicAdd(&a.cnt[c], 1);
        a.edges1[p1] = make_int2(r, __float_as_int(a.sup1w[e]));
        int p2 = atomicAdd(&a.cnt[N_NODES + r], 1);
        a.edges2[p2] = make_int2(c, __float_as_int(a.sup2w[e]));
    }
    gbar(a.barrier, ++phase * GRID);

    const u32* S0 = (const u32*)a.S;
    u32* X1 = (u32*)(a.S + 1 * SLAB);
    u32* X2 = (u32*)(a.S + 2 * SLAB);
    u32* X3 = (u32*)(a.S + 3 * SLAB);
    u32* X4 = (u32*)(a.S + 4 * SLAB);

    // phase 5: X1 = S1@X0, X3 = S2@X0
    spmm_phase(S0, nullptr, X1, S0, nullptr, X3,
               a.rowptr1, a.edges1, a.rowptr2, a.edges2, 1.f, 0.f);
    gbar(a.barrier, ++phase * GRID);

    // phase 6: X2 = 2*S1@X1 - X0, X4 = 2*S2@X3 - X0
    spmm_phase(X1, S0, X2, X3, S0, X4,
               a.rowptr1, a.edges1, a.rowptr2, a.edges2, 2.f, -1.f);
    gbar(a.barrier, ++phase * GRID);

    // phase 7: theta = sigmoid(X@W_lat+b_lat), H0 = tanh(X@W_units+b_units)
    gemm12_phase(a.S, a.bpk12, a.b_lat, a.b_units, a.theta, a.H0);
    gbar(a.barrier, ++phase * GRID);

    // phase 8: [Q|P1..P4] = H0 @ bpkP (+b_lat on Q), overlays S
    gemmP_phase(a.H0, a.bpkP, a.b_lat, a.S);
    gbar(a.barrier, ++phase * GRID);

    const u32* Q  = (const u32*)(a.S + 0 * SLAB);
    const u32* P1 = (const u32*)(a.S + 1 * SLAB);
    const u32* P2 = (const u32*)(a.S + 2 * SLAB);
    const u32* P3 = (const u32*)(a.S + 3 * SLAB);
    const u32* P4 = (const u32*)(a.S + 4 * SLAB);

    // phase 9: T1 = P1 + 2*S1@P2 ; T2 = P3 + 2*S2@P4
    spmm_phase(P2, P1, (u32*)a.T1, P4, P3, (u32*)a.T2,
               a.rowptr1, a.edges1, a.rowptr2, a.edges2, 2.f, 1.f);
    gbar(a.barrier, ++phase * GRID);

    // phase 10: out = -theta * tanh(Q + S1@T1 + S2@T2)
    final_phase((const u32*)a.T1, (const u32*)a.T2, Q, (const u32*)a.theta,
                a.rowptr1, a.edges1, a.rowptr2, a.edges2, a.out);
}

// ---------------- launch ----------------
extern "C" void kernel_launch(void* const* d_in, const int* in_sizes, int n_in,
                              void* d_out, int out_size, void* d_ws, size_t ws_size,
                              hipStream_t stream) {
    char* ws = (char*)d_ws;
    size_t off = 0;
    auto alloc = [&](size_t bytes) -> void* {
        void* p = ws + off;
        off += (bytes + 511) & ~(size_t)511;
        return p;
    };

    MegaArgs ma;
    ma.y       = (const float2*)d_in[0];
    ma.W_lat   = (const float*)d_in[1];
    ma.b_lat   = (const float*)d_in[2];
    ma.W_units = (const float*)d_in[3];
    ma.b_units = (const float*)d_in[4];
    ma.W_final = (const float*)d_in[5];
    ma.sup1w   = (const float*)d_in[6];
    ma.sup2w   = (const float*)d_in[7];
    ma.rows    = (const int*)d_in[8];
    ma.cols    = (const int*)d_in[9];
    ma.out     = (float*)d_out;

    ma.rowptr1 = (int*)alloc((N_NODES + 1) * 4);
    ma.rowptr2 = (int*)alloc((N_NODES + 1) * 4);
    ma.cnt     = (int*)alloc((size_t)2 * N_NODES * 4);
    ma.bsums   = (int*)alloc(80 * 4);
    ma.barrier = (int*)alloc(64 * 4);
    ma.edges1  = (int2*)alloc((size_t)NEDGE * 8);
    ma.edges2  = (int2*)alloc((size_t)NEDGE * 8);
    ma.bpk12   = (u16*)alloc((size_t)61440 * 2);
    ma.bpkP    = (u16*)alloc((size_t)40960 * 2);
    ma.theta   = (u16*)alloc((size_t)NB * 64 * 2);
    ma.S       = (u16*)alloc((size_t)5 * NB * 64 * 2);  // X-slabs, later Q/P slabs
    ma.H0      = (u16*)alloc((size_t)NB * 128 * 2);
    ma.T1      = (u16*)alloc((size_t)NB * 64 * 2);
    ma.T2      = (u16*)alloc((size_t)NB * 64 * 2);

    hipMemsetAsync(ma.barrier, 0, 64 * 4, stream);
    mega_kernel<<<GRID, 256, 0, stream>>>(ma);
}

// Round 10
// 767.729 us; speedup vs baseline: 3.7308x; 3.7308x over previous
//
#include <hip/hip_runtime.h>

#define N_NODES 10000
#define NEDGE 160000
#define NB 80000  /* N_NODES*BATCH */
#define GRID1 1024 /* csr_kernel: 4 blocks/CU x 256 CUs co-resident via __launch_bounds__(256,4) */

typedef unsigned int u32;
typedef unsigned short u16;
typedef __attribute__((ext_vector_type(8))) short short8;
typedef __attribute__((ext_vector_type(4))) float float4v;

__device__ __forceinline__ u16 f2bf(float f) {
    u32 u = __float_as_uint(f);
    return (u16)((u + 0x7fffu + ((u >> 16) & 1u)) >> 16);
}
__device__ __forceinline__ float lo16(u32 u) { return __uint_as_float(u << 16); }
__device__ __forceinline__ float hi16(u32 u) { return __uint_as_float(u & 0xffff0000u); }
__device__ __forceinline__ u32 pack2(float a, float b) {
    return (u32)f2bf(a) | (((u32)f2bf(b)) << 16);
}
__device__ __forceinline__ float fast_tanh(float v) {
    return 1.f - 2.f / (__expf(2.f * v) + 1.f);
}

// software grid barrier (R9-proven correct); only used inside the tiny csr_kernel
__device__ __forceinline__ void gbar(int* ctr, int target) {
    __syncthreads();
    if (threadIdx.x == 0) {
        __threadfence();
        __hip_atomic_fetch_add(ctr, 1, __ATOMIC_RELEASE, __HIP_MEMORY_SCOPE_AGENT);
        while (__hip_atomic_load(ctr, __ATOMIC_ACQUIRE, __HIP_MEMORY_SCOPE_AGENT) < target)
            __builtin_amdgcn_s_sleep(2);
        __threadfence();
    }
    __syncthreads();
}

static const size_t SLAB = (size_t)NB * 64;  // u16 elems per 64-wide slab

// ---------------- csr_kernel: prep + count | blocksum | scanapply | scatter ----------
__global__ __launch_bounds__(256, 4) void csr_kernel(
    const float2* __restrict__ y, u32* __restrict__ X0,
    const float* __restrict__ W_lat, const float* __restrict__ W_units,
    u16* __restrict__ bpk12, const float* __restrict__ W_final, u16* __restrict__ bpkP,
    const int* __restrict__ rows, const int* __restrict__ cols,
    const float* __restrict__ sup1w, const float* __restrict__ sup2w,
    int* __restrict__ cnt, int* __restrict__ bsums, int* __restrict__ barrier,
    int* __restrict__ rowptr1, int* __restrict__ rowptr2,
    int2* __restrict__ edges1, int2* __restrict__ edges2) {
    __shared__ int sh[256];
    int t = threadIdx.x;

    // phase 0: transpose + bpack12 + bpackP + count (independent works, one pass)
    for (int wb = blockIdx.x; wb < 11025; wb += GRID1) {
        if (wb < 10000) {
            int idx = wb * 256 + t;  // NB*32 outputs
            int fh = idx & 31;
            int rb = idx >> 5;
            int bb = rb & 7;
            int n = rb >> 3;
            float2 v = y[((size_t)bb * N_NODES + n) * 32 + fh];
            X0[idx] = pack2(v.x, v.y);
        } else if (wb < 10240) {
            int idx = (wb - 10000) * 256 + t;  // < 61440
            int j = idx & 7;
            int lane = (idx >> 3) & 63;
            int rest = idx >> 9;
            int ct = rest % 12;
            int ks = rest / 12;
            int k = ks * 32 + (lane >> 4) * 8 + j;
            int col = ct * 16 + (lane & 15);
            int wrow = (k % 64) * 5 + (k / 64);
            float v = (col < 64) ? W_lat[wrow * 64 + col] : W_units[wrow * 128 + (col - 64)];
            bpk12[idx] = f2bf(v);
        } else if (wb < 10400) {
            int idx = (wb - 10240) * 256 + t;  // < 40960
            int j8 = idx & 7;
            int lane = (idx >> 3) & 63;
            int rest = idx >> 9;
            int ct = rest % 20;
            int ks = rest / 20;
            int k = ks * 32 + (lane >> 4) * 8 + j8;
            int col = ct * 16 + (lane & 15);
            int slot = col >> 6, j = col & 63;
            float v;
            if (slot == 0)
                v = W_final[(k * 5 + 0) * 64 + j] - W_final[(k * 5 + 2) * 64 + j] -
                    W_final[(k * 5 + 4) * 64 + j];
            else
                v = W_final[(k * 5 + slot) * 64 + j];
            bpkP[idx] = f2bf(v);
        } else {
            int e = (wb - 10400) * 256 + t;  // 625*256 == NEDGE
            atomicAdd(&cnt[cols[e]], 1);            // support1: dst=cols
            atomicAdd(&cnt[N_NODES + rows[e]], 1);  // support2: dst=rows
        }
    }
    gbar(barrier, GRID1);

    // phase 1: per-chunk block sums (80 chunks: arr*40 + c)
    for (int wb = blockIdx.x; wb < 80; wb += GRID1) {
        int arr = wb / 40, c = wb % 40;
        int idx = c * 256 + t;
        int v = (idx < N_NODES) ? cnt[arr * N_NODES + idx] : 0;
#pragma unroll
        for (int off = 32; off; off >>= 1) v += __shfl_down(v, off, 64);
        int wv = t >> 6, ln = t & 63;
        if (ln == 0) sh[wv] = v;
        __syncthreads();
        if (t == 0) bsums[wb] = sh[0] + sh[1] + sh[2] + sh[3];
        __syncthreads();
    }
    gbar(barrier, 2 * GRID1);

    // phase 2: scanapply with serial prefix of the 40 partials per array
    for (int wb = blockIdx.x; wb < 80; wb += GRID1) {
        int arr = wb / 40, c = wb % 40;
        int base = 0;
        for (int i = 0; i < c; i++) base += bsums[arr * 40 + i];
        int idx = c * 256 + t;
        bool ok = idx < N_NODES;
        int v = ok ? cnt[arr * N_NODES + idx] : 0;
        sh[t] = v;
        __syncthreads();
        for (int off = 1; off < 256; off <<= 1) {
            int add = (t >= off) ? sh[t - off] : 0;
            __syncthreads();
            sh[t] += add;
            __syncthreads();
        }
        int excl = sh[t] - v + base;
        if (ok) {
            int* rp = arr ? rowptr2 : rowptr1;
            rp[idx] = excl;
            cnt[arr * N_NODES + idx] = excl;  // cursor
        }
        __syncthreads();
    }
    if (blockIdx.x == 0 && t == 0) {
        rowptr1[N_NODES] = NEDGE;
        rowptr2[N_NODES] = NEDGE;
    }
    gbar(barrier, 3 * GRID1);

    // phase 3: scatter
    for (int wb = blockIdx.x; wb < 625; wb += GRID1) {
        int e = wb * 256 + t;
        int r = rows[e], c = cols[e];
        int p1 = atomicAdd(&cnt[c], 1);
        edges1[p1] = make_int2(r, __float_as_int(sup1w[e]));
        int p2 = atomicAdd(&cnt[N_NODES + r], 1);
        edges2[p2] = make_int2(c, __float_as_int(sup2w[e]));
    }
}

// ---------------- SpMM gather: full-width row, 4-deep MLP unroll (R6-proven) --------
__device__ __forceinline__ void gacc(float* acc, float w, uint4 u) {
    acc[0] += w * lo16(u.x); acc[1] += w * hi16(u.x);
    acc[2] += w * lo16(u.y); acc[3] += w * hi16(u.y);
    acc[4] += w * lo16(u.z); acc[5] += w * hi16(u.z);
    acc[6] += w * lo16(u.w); acc[7] += w * hi16(u.w);
}

__device__ __forceinline__ void gather_row(const u32* __restrict__ Xin,
                                           const int* __restrict__ rp,
                                           const int2* __restrict__ eg,
                                           int n, int lane, float* acc) {
    int e0 = rp[n], e1 = rp[n + 1];
    for (int base = e0; base < e1; base += 64) {
        int m = min(64, e1 - base);
        int2 me = make_int2(0, 0);
        if (lane < m) me = eg[base + lane];
        int j = 0;
        for (; j + 4 <= m; j += 4) {
            int s0 = __shfl(me.x, j, 64);
            int s1 = __shfl(me.x, j + 1, 64);
            int s2 = __shfl(me.x, j + 2, 64);
            int s3 = __shfl(me.x, j + 3, 64);
            float w0 = __int_as_float(__shfl(me.y, j, 64));
            float w1 = __int_as_float(__shfl(me.y, j + 1, 64));
            float w2 = __int_as_float(__shfl(me.y, j + 2, 64));
            float w3 = __int_as_float(__shfl(me.y, j + 3, 64));
            uint4 u0 = *(const uint4*)(Xin + (size_t)s0 * 256 + lane * 4);
            uint4 u1 = *(const uint4*)(Xin + (size_t)s1 * 256 + lane * 4);
            uint4 u2 = *(const uint4*)(Xin + (size_t)s2 * 256 + lane * 4);
            uint4 u3 = *(const uint4*)(Xin + (size_t)s3 * 256 + lane * 4);
            gacc(acc, w0, u0);
            gacc(acc, w1, u1);
            gacc(acc, w2, u2);
            gacc(acc, w3, u3);
        }
        for (; j < m; j++) {
            int src = __shfl(me.x, j, 64);
            float w = __int_as_float(__shfl(me.y, j, 64));
            uint4 u = *(const uint4*)(Xin + (size_t)src * 256 + lane * 4);
            gacc(acc, w, u);
        }
    }
}

__global__ __launch_bounds__(256) void spmm2_kernel(
    const u32* __restrict__ XinA, const u32* __restrict__ XprevA, u32* __restrict__ XoutA,
    const u32* __restrict__ XinB, const u32* __restrict__ XprevB, u32* __restrict__ XoutB,
    const int* __restrict__ rowptr1, const int2* __restrict__ edges1,
    const int* __restrict__ rowptr2, const int2* __restrict__ edges2,
    float alpha, float beta) {
    int lane = threadIdx.x & 63;
    int v = blockIdx.x * 4 + (threadIdx.x >> 6);
    if (v >= 2 * N_NODES) return;
    bool hB = v >= N_NODES;
    int n = hB ? v - N_NODES : v;
    const u32* Xin = hB ? XinB : XinA;
    const u32* Xprev = hB ? XprevB : XprevA;
    u32* Xout = hB ? XoutB : XoutA;
    const int* rp = hB ? rowptr2 : rowptr1;
    const int2* eg = hB ? edges2 : edges1;

    float acc[8] = {0.f, 0.f, 0.f, 0.f, 0.f, 0.f, 0.f, 0.f};
    gather_row(Xin, rp, eg, n, lane, acc);

    size_t o = (size_t)n * 256 + lane * 4;
    if (beta != 0.f) {
        uint4 p = *(const uint4*)(Xprev + o);
        acc[0] = alpha * acc[0] + beta * lo16(p.x); acc[1] = alpha * acc[1] + beta * hi16(p.x);
        acc[2] = alpha * acc[2] + beta * lo16(p.y); acc[3] = alpha * acc[3] + beta * hi16(p.y);
        acc[4] = alpha * acc[4] + beta * lo16(p.z); acc[5] = alpha * acc[5] + beta * hi16(p.z);
        acc[6] = alpha * acc[6] + beta * lo16(p.w); acc[7] = alpha * acc[7] + beta * hi16(p.w);
    } else {
#pragma unroll
        for (int i = 0; i < 8; i++) acc[i] *= alpha;
    }
    uint4 r;
    r.x = pack2(acc[0], acc[1]);
    r.y = pack2(acc[2], acc[3]);
    r.z = pack2(acc[4], acc[5]);
    r.w = pack2(acc[6], acc[7]);
    *(uint4*)(Xout + o) = r;
}

// final: out = -theta * tanh(Q + S1@T1 + S2@T2), fp32 (B,N,64) layout
__global__ __launch_bounds__(256) void spmm_final_kernel(
    const u32* __restrict__ T1, const u32* __restrict__ T2,
    const u32* __restrict__ Q, const u32* __restrict__ theta,
    const int* __restrict__ rowptr1, const int2* __restrict__ edges1,
    const int* __restrict__ rowptr2, const int2* __restrict__ edges2,
    float* __restrict__ outF) {
    int lane = threadIdx.x & 63;
    int n = blockIdx.x * 4 + (threadIdx.x >> 6);
    if (n >= N_NODES) return;

    float acc[8] = {0.f, 0.f, 0.f, 0.f, 0.f, 0.f, 0.f, 0.f};
    gather_row(T1, rowptr1, edges1, n, lane, acc);
    gather_row(T2, rowptr2, edges2, n, lane, acc);

    size_t o = (size_t)n * 256 + lane * 4;
    uint4 q = *(const uint4*)(Q + o);
    uint4 th = *(const uint4*)(theta + o);
    float res[8];
    res[0] = -lo16(th.x) * fast_tanh(lo16(q.x) + acc[0]);
    res[1] = -hi16(th.x) * fast_tanh(hi16(q.x) + acc[1]);
    res[2] = -lo16(th.y) * fast_tanh(lo16(q.y) + acc[2]);
    res[3] = -hi16(th.y) * fast_tanh(hi16(q.y) + acc[3]);
    res[4] = -lo16(th.z) * fast_tanh(lo16(q.z) + acc[4]);
    res[5] = -hi16(th.z) * fast_tanh(hi16(q.z) + acc[5]);
    res[6] = -lo16(th.w) * fast_tanh(lo16(q.w) + acc[6]);
    res[7] = -hi16(th.w) * fast_tanh(hi16(q.w) + acc[7]);
    int b = lane >> 3;
    int f0 = ((lane * 4) & 31) * 2;
    float* dst = outF + (size_t)b * (N_NODES * 64) + (size_t)n * 64 + f0;
    *(float4*)(dst) = make_float4(res[0], res[1], res[2], res[3]);
    *(float4*)(dst + 4) = make_float4(res[4], res[5], res[6], res[7]);
}

// ---------------- MFMA GEMM: 64 rows/block (4 waves x 16 rows), optional col-split ---
struct Slabs { const u16* p[5]; };

// MODE 0: plain (+bias1 on cols<64) -> 64-wide slabs at O1
// MODE 1: fused: col<64 sigmoid(+bias1)->O1 (64-wide); col>=64 tanh(+bias2)->O2 (128-wide)
template <int FIN, int NM, int NOUT, int NSPLIT, int MODE>
__global__ __launch_bounds__(256) void gemm_kernel(
    Slabs A, const u16* __restrict__ Bp, const float* __restrict__ bias1,
    const float* __restrict__ bias2, u16* __restrict__ O1, u16* __restrict__ O2) {
    constexpr int K = NM * FIN;
    constexpr int KS = K / 32;
    constexpr int CTT = NOUT / 16;
    constexpr int CT = CTT / NSPLIT;
    int lane = threadIdx.x & 63;
    int wave = threadIdx.x >> 6;
    int rowBase = (blockIdx.x / NSPLIT) * 64 + wave * 16;
    int ctBase = (blockIdx.x % NSPLIT) * CT;
    int mrow = lane & 15;
    int kq = lane >> 4;

    float4v acc[CT];
#pragma unroll
    for (int c = 0; c < CT; c++) acc[c] = (float4v){0.f, 0.f, 0.f, 0.f};

#pragma unroll
    for (int ks = 0; ks < KS; ks++) {
        int k = ks * 32 + kq * 8;
        int m = k / FIN;  // uniform within ks
        int koff = k % FIN;
        short8 a = *(const short8*)(A.p[m] + (size_t)(rowBase + mrow) * FIN + koff);
        short8 b[CT];
#pragma unroll
        for (int ct = 0; ct < CT; ct++)
            b[ct] = *(const short8*)(Bp + ((size_t)(ks * CTT + ctBase + ct) * 64 + lane) * 8);
#pragma unroll
        for (int ct = 0; ct < CT; ct++)
            acc[ct] = __builtin_amdgcn_mfma_f32_16x16x32_bf16(a, b[ct], acc[ct], 0, 0, 0);
    }

    int rowq = rowBase + kq * 4;
#pragma unroll
    for (int ct = 0; ct < CT; ct++) {
        int col = (ctBase + ct) * 16 + mrow;
        float bsv;
        if (MODE == 0) bsv = (col < 64) ? bias1[col] : 0.f;
        else bsv = (col < 64) ? bias1[col] : bias2[col - 64];
#pragma unroll
        for (int i = 0; i < 4; i++) {
            float v = acc[ct][i] + bsv;
            int r = rowq + i;
            if (MODE == 0) {
                O1[(size_t)(col >> 6) * SLAB + (size_t)r * 64 + (col & 63)] = f2bf(v);
            } else {
                if (col < 64) {
                    v = 1.f / (1.f + __expf(-v));
                    O1[(size_t)r * 64 + col] = f2bf(v);
                } else {
                    O2[(size_t)r * 128 + (col - 64)] = f2bf(fast_tanh(v));
                }
            }
        }
    }
}

// ---------------- launch ----------------
extern "C" void kernel_launch(void* const* d_in, const int* in_sizes, int n_in,
                              void* d_out, int out_size, void* d_ws, size_t ws_size,
                              hipStream_t stream) {
    const float2* y    = (const float2*)d_in[0];
    const float* W_lat = (const float*)d_in[1];
    const float* b_lat = (const float*)d_in[2];
    const float* W_units = (const float*)d_in[3];
    const float* b_units = (const float*)d_in[4];
    const float* W_final = (const float*)d_in[5];
    const float* sup1w = (const float*)d_in[6];
    const float* sup2w = (const float*)d_in[7];
    const int* rows    = (const int*)d_in[8];
    const int* cols    = (const int*)d_in[9];
    float* out = (float*)d_out;

    char* ws = (char*)d_ws;
    size_t off = 0;
    auto alloc = [&](size_t bytes) -> void* {
        void* p = ws + off;
        off += (bytes + 511) & ~(size_t)511;
        return p;
    };
    int* rowptr1 = (int*)alloc((N_NODES + 1) * 4);
    int* rowptr2 = (int*)alloc((N_NODES + 1) * 4);
    int* cnt = (int*)alloc((size_t)2 * N_NODES * 4);  // zeroed by memset below
    int* barrier = (int*)alloc(1024);                 // contiguous with cnt: one memset
    int* bsums = (int*)alloc(80 * 4);
    int2* edges1 = (int2*)alloc((size_t)NEDGE * 8);
    int2* edges2 = (int2*)alloc((size_t)NEDGE * 8);
    u16* bpk12 = (u16*)alloc((size_t)61440 * 2);
    u16* bpkP = (u16*)alloc((size_t)40960 * 2);
    u16* theta = (u16*)alloc((size_t)NB * 64 * 2);
    u16* S = (u16*)alloc((size_t)5 * NB * 64 * 2);  // X-slabs, later Q/P slabs
    u16* H0 = (u16*)alloc((size_t)NB * 128 * 2);
    u16* T1 = (u16*)alloc((size_t)NB * 64 * 2);
    u16* T2 = (u16*)alloc((size_t)NB * 64 * 2);

    // zero cnt (80000 B, padded to 80384) + barrier (1024 B) in one memset
    hipMemsetAsync(cnt, 0, 80384 + 1024, stream);

    csr_kernel<<<GRID1, 256, 0, stream>>>(y, (u32*)S, W_lat, W_units, bpk12, W_final, bpkP,
                                          rows, cols, sup1w, sup2w, cnt, bsums, barrier,
                                          rowptr1, rowptr2, edges1, edges2);

    // x-side diffusion: X1 = S1@X0, X3 = S2@X0 ; X2 = 2*S1@X1 - X0, X4 = 2*S2@X3 - X0
    const u32* S0 = (const u32*)S;
    u32* X1 = (u32*)(S + 1 * SLAB);
    u32* X2 = (u32*)(S + 2 * SLAB);
    u32* X3 = (u32*)(S + 3 * SLAB);
    u32* X4 = (u32*)(S + 4 * SLAB);
    spmm2_kernel<<<5000, 256, 0, stream>>>(S0, nullptr, X1, S0, nullptr, X3,
                                           rowptr1, edges1, rowptr2, edges2, 1.f, 0.f);
    spmm2_kernel<<<5000, 256, 0, stream>>>(X1, S0, X2, X3, S0, X4,
                                           rowptr1, edges1, rowptr2, edges2, 2.f, -1.f);

    Slabs SX;
    for (int m = 0; m < 5; m++) SX.p[m] = S + (size_t)m * SLAB;
    // fused: theta = sigmoid(X@W_lat + b_lat), H0 = tanh(X@W_units + b_units)
    gemm_kernel<64, 5, 192, 1, 1><<<1250, 256, 0, stream>>>(SX, bpk12, b_lat, b_units, theta, H0);

    // P-GEMM: [Q|P1|P2|P3|P4] = H0 @ bpkP (Q = P0-P2-P4 + b_lat), overlays S
    Slabs SH;
    SH.p[0] = H0;
    gemm_kernel<128, 1, 320, 2, 0><<<2500, 256, 0, stream>>>(SH, bpkP, b_lat, nullptr, S, nullptr);

    const u32* Q  = (const u32*)(S + 0 * SLAB);
    const u32* P1 = (const u32*)(S + 1 * SLAB);
    const u32* P2 = (const u32*)(S + 2 * SLAB);
    const u32* P3 = (const u32*)(S + 3 * SLAB);
    const u32* P4 = (const u32*)(S + 4 * SLAB);
    // T1 = P1 + 2*S1@P2 ; T2 = P3 + 2*S2@P4
    spmm2_kernel<<<5000, 256, 0, stream>>>(P2, P1, (u32*)T1, P4, P3, (u32*)T2,
                                           rowptr1, edges1, rowptr2, edges2, 2.f, 1.f);
    // out = -theta * tanh(Q + S1@T1 + S2@T2)
    spmm_final_kernel<<<2500, 256, 0, stream>>>((const u32*)T1, (const u32*)T2, Q,
                                                (const u32*)theta,
                                                rowptr1, edges1, rowptr2, edges2, out);
}

// Round 11
// 347.163 us; speedup vs baseline: 8.2505x; 2.2114x over previous
//
#include <hip/hip_runtime.h>

#define N_NODES 10000
#define NEDGE 160000
#define NB 80000  /* N_NODES*BATCH */

typedef unsigned int u32;
typedef unsigned short u16;
typedef __attribute__((ext_vector_type(8))) short short8;
typedef __attribute__((ext_vector_type(4))) float float4v;

__device__ __forceinline__ u16 f2bf(float f) {
    u32 u = __float_as_uint(f);
    return (u16)((u + 0x7fffu + ((u >> 16) & 1u)) >> 16);
}
__device__ __forceinline__ float lo16(u32 u) { return __uint_as_float(u << 16); }
__device__ __forceinline__ float hi16(u32 u) { return __uint_as_float(u & 0xffff0000u); }
__device__ __forceinline__ u32 pack2(float a, float b) {
    return (u32)f2bf(a) | (((u32)f2bf(b)) << 16);
}
__device__ __forceinline__ float fast_tanh(float v) {
    return 1.f - 2.f / (__expf(2.f * v) + 1.f);
}

static const size_t SLAB = (size_t)NB * 64;  // u16 elems per 64-wide slab

// ---------------- prep+count: transpose + bpack12 + bpackP + degree count -----------
__global__ __launch_bounds__(256) void prepcount_kernel(
    const float2* __restrict__ y, u32* __restrict__ X0,
    const float* __restrict__ W_lat, const float* __restrict__ W_units,
    u16* __restrict__ bpk12, const float* __restrict__ W_final, u16* __restrict__ bpkP,
    const int* __restrict__ rows, const int* __restrict__ cols, int* __restrict__ cnt) {
    int b = blockIdx.x, t = threadIdx.x;
    if (b < 10000) {
        int idx = b * 256 + t;  // NB*32 outputs exactly
        int fh = idx & 31;
        int rb = idx >> 5;
        int bb = rb & 7;
        int n = rb >> 3;
        float2 v = y[((size_t)bb * N_NODES + n) * 32 + fh];
        X0[idx] = pack2(v.x, v.y);
    } else if (b < 10240) {
        // fused bpack: K=320 (k=m*64+f, wrow=f*5+m), NOUT=192 (0..63 lat, 64..191 units)
        int idx = (b - 10000) * 256 + t;  // < 61440
        int j = idx & 7;
        int lane = (idx >> 3) & 63;
        int rest = idx >> 9;
        int ct = rest % 12;
        int ks = rest / 12;
        int k = ks * 32 + (lane >> 4) * 8 + j;
        int col = ct * 16 + (lane & 15);
        int wrow = (k % 64) * 5 + (k / 64);
        float v = (col < 64) ? W_lat[wrow * 64 + col] : W_units[wrow * 128 + (col - 64)];
        bpk12[idx] = f2bf(v);
    } else if (b < 10400) {
        // bpackP: K=128, NOUT=320; slot0 = W[:,0]-W[:,2]-W[:,4], slot m>=1 = W[:,m]
        int idx = (b - 10240) * 256 + t;  // < 40960
        int j8 = idx & 7;
        int lane = (idx >> 3) & 63;
        int rest = idx >> 9;
        int ct = rest % 20;
        int ks = rest / 20;
        int k = ks * 32 + (lane >> 4) * 8 + j8;
        int col = ct * 16 + (lane & 15);
        int slot = col >> 6, j = col & 63;
        float v;
        if (slot == 0)
            v = W_final[(k * 5 + 0) * 64 + j] - W_final[(k * 5 + 2) * 64 + j] -
                W_final[(k * 5 + 4) * 64 + j];
        else
            v = W_final[(k * 5 + slot) * 64 + j];
        bpkP[idx] = f2bf(v);
    } else {
        int e = (b - 10400) * 256 + t;  // 625*256 == NEDGE exactly
        atomicAdd(&cnt[cols[e]], 1);            // support1: dst=cols
        atomicAdd(&cnt[N_NODES + rows[e]], 1);  // support2: dst=rows
    }
}

// 80 blocks: per-chunk sums
__global__ void blocksum_kernel(const int* __restrict__ cnt, int* __restrict__ bsums) {
    __shared__ int red[4];
    int arr = blockIdx.x / 40;
    int c = blockIdx.x % 40;
    int idx = c * 256 + threadIdx.x;
    int v = (idx < N_NODES) ? cnt[arr * N_NODES + idx] : 0;
#pragma unroll
    for (int off = 32; off; off >>= 1) v += __shfl_down(v, off, 64);
    int wv = threadIdx.x >> 6, ln = threadIdx.x & 63;
    if (ln == 0) red[wv] = v;
    __syncthreads();
    if (threadIdx.x == 0) bsums[blockIdx.x] = red[0] + red[1] + red[2] + red[3];
}

// 80 blocks: local scan + serial prefix over chunk sums -> rowptr + cursor
__global__ void scanapply_kernel(int* __restrict__ cnt, const int* __restrict__ bsums,
                                 int* __restrict__ rowptr1, int* __restrict__ rowptr2) {
    __shared__ int lds[256];
    int arr = blockIdx.x / 40;
    int c = blockIdx.x % 40;
    int base = 0;
    for (int i = 0; i < c; i++) base += bsums[arr * 40 + i];  // 40-deep serial, L2-hot
    int idx = c * 256 + threadIdx.x;
    bool ok = idx < N_NODES;
    int v = ok ? cnt[arr * N_NODES + idx] : 0;
    int t = threadIdx.x;
    lds[t] = v;
    __syncthreads();
    for (int off = 1; off < 256; off <<= 1) {
        int add = (t >= off) ? lds[t - off] : 0;
        __syncthreads();
        lds[t] += add;
        __syncthreads();
    }
    int excl = lds[t] - v + base;
    if (ok) {
        int* rp = arr ? rowptr2 : rowptr1;
        rp[idx] = excl;
        cnt[arr * N_NODES + idx] = excl;  // cursor
    }
    if (blockIdx.x == 0 && t == 0) {
        rowptr1[N_NODES] = NEDGE;
        rowptr2[N_NODES] = NEDGE;
    }
}

__global__ void scatter_kernel(const int* __restrict__ rows, const int* __restrict__ cols,
                               const float* __restrict__ w1, const float* __restrict__ w2,
                               int* __restrict__ cur1, int* __restrict__ cur2,
                               int2* __restrict__ edges1, int2* __restrict__ edges2) {
    int e = blockIdx.x * 256 + threadIdx.x;
    if (e < NEDGE) {
        int r = rows[e], c = cols[e];
        int p1 = atomicAdd(&cur1[c], 1);
        edges1[p1] = make_int2(r, __float_as_int(w1[e]));
        int p2 = atomicAdd(&cur2[r], 1);
        edges2[p2] = make_int2(c, __float_as_int(w2[e]));
    }
}

// ---------------- SpMM gather: full-width row, 4-deep MLP unroll (R6-proven) --------
__device__ __forceinline__ void gacc(float* acc, float w, uint4 u) {
    acc[0] += w * lo16(u.x); acc[1] += w * hi16(u.x);
    acc[2] += w * lo16(u.y); acc[3] += w * hi16(u.y);
    acc[4] += w * lo16(u.z); acc[5] += w * hi16(u.z);
    acc[6] += w * lo16(u.w); acc[7] += w * hi16(u.w);
}

__device__ __forceinline__ void gather_row(const u32* __restrict__ Xin,
                                           const int* __restrict__ rp,
                                           const int2* __restrict__ eg,
                                           int n, int lane, float* acc) {
    int e0 = rp[n], e1 = rp[n + 1];
    for (int base = e0; base < e1; base += 64) {
        int m = min(64, e1 - base);
        int2 me = make_int2(0, 0);
        if (lane < m) me = eg[base + lane];
        int j = 0;
        for (; j + 4 <= m; j += 4) {
            int s0 = __shfl(me.x, j, 64);
            int s1 = __shfl(me.x, j + 1, 64);
            int s2 = __shfl(me.x, j + 2, 64);
            int s3 = __shfl(me.x, j + 3, 64);
            float w0 = __int_as_float(__shfl(me.y, j, 64));
            float w1 = __int_as_float(__shfl(me.y, j + 1, 64));
            float w2 = __int_as_float(__shfl(me.y, j + 2, 64));
            float w3 = __int_as_float(__shfl(me.y, j + 3, 64));
            uint4 u0 = *(const uint4*)(Xin + (size_t)s0 * 256 + lane * 4);
            uint4 u1 = *(const uint4*)(Xin + (size_t)s1 * 256 + lane * 4);
            uint4 u2 = *(const uint4*)(Xin + (size_t)s2 * 256 + lane * 4);
            uint4 u3 = *(const uint4*)(Xin + (size_t)s3 * 256 + lane * 4);
            gacc(acc, w0, u0);
            gacc(acc, w1, u1);
            gacc(acc, w2, u2);
            gacc(acc, w3, u3);
        }
        for (; j < m; j++) {
            int src = __shfl(me.x, j, 64);
            float w = __int_as_float(__shfl(me.y, j, 64));
            uint4 u = *(const uint4*)(Xin + (size_t)src * 256 + lane * 4);
            gacc(acc, w, u);
        }
    }
}

__global__ __launch_bounds__(256) void spmm2_kernel(
    const u32* __restrict__ XinA, const u32* __restrict__ XprevA, u32* __restrict__ XoutA,
    const u32* __restrict__ XinB, const u32* __restrict__ XprevB, u32* __restrict__ XoutB,
    const int* __restrict__ rowptr1, const int2* __restrict__ edges1,
    const int* __restrict__ rowptr2, const int2* __restrict__ edges2,
    float alpha, float beta) {
    int lane = threadIdx.x & 63;
    int v = blockIdx.x * 4 + (threadIdx.x >> 6);
    if (v >= 2 * N_NODES) return;
    bool hB = v >= N_NODES;
    int n = hB ? v - N_NODES : v;
    const u32* Xin = hB ? XinB : XinA;
    const u32* Xprev = hB ? XprevB : XprevA;
    u32* Xout = hB ? XoutB : XoutA;
    const int* rp = hB ? rowptr2 : rowptr1;
    const int2* eg = hB ? edges2 : edges1;

    float acc[8] = {0.f, 0.f, 0.f, 0.f, 0.f, 0.f, 0.f, 0.f};
    gather_row(Xin, rp, eg, n, lane, acc);

    size_t o = (size_t)n * 256 + lane * 4;
    if (beta != 0.f) {
        uint4 p = *(const uint4*)(Xprev + o);
        acc[0] = alpha * acc[0] + beta * lo16(p.x); acc[1] = alpha * acc[1] + beta * hi16(p.x);
        acc[2] = alpha * acc[2] + beta * lo16(p.y); acc[3] = alpha * acc[3] + beta * hi16(p.y);
        acc[4] = alpha * acc[4] + beta * lo16(p.z); acc[5] = alpha * acc[5] + beta * hi16(p.z);
        acc[6] = alpha * acc[6] + beta * lo16(p.w); acc[7] = alpha * acc[7] + beta * hi16(p.w);
    } else {
#pragma unroll
        for (int i = 0; i < 8; i++) acc[i] *= alpha;
    }
    uint4 r;
    r.x = pack2(acc[0], acc[1]);
    r.y = pack2(acc[2], acc[3]);
    r.z = pack2(acc[4], acc[5]);
    r.w = pack2(acc[6], acc[7]);
    *(uint4*)(Xout + o) = r;
}

// final: out = -theta * tanh(Q + S1@T1 + S2@T2), fp32 (B,N,64) layout
__global__ __launch_bounds__(256) void spmm_final_kernel(
    const u32* __restrict__ T1, const u32* __restrict__ T2,
    const u32* __restrict__ Q, const u32* __restrict__ theta,
    const int* __restrict__ rowptr1, const int2* __restrict__ edges1,
    const int* __restrict__ rowptr2, const int2* __restrict__ edges2,
    float* __restrict__ outF) {
    int lane = threadIdx.x & 63;
    int n = blockIdx.x * 4 + (threadIdx.x >> 6);
    if (n >= N_NODES) return;

    float acc[8] = {0.f, 0.f, 0.f, 0.f, 0.f, 0.f, 0.f, 0.f};
    gather_row(T1, rowptr1, edges1, n, lane, acc);
    gather_row(T2, rowptr2, edges2, n, lane, acc);

    size_t o = (size_t)n * 256 + lane * 4;
    uint4 q = *(const uint4*)(Q + o);
    uint4 th = *(const uint4*)(theta + o);
    float res[8];
    res[0] = -lo16(th.x) * fast_tanh(lo16(q.x) + acc[0]);
    res[1] = -hi16(th.x) * fast_tanh(hi16(q.x) + acc[1]);
    res[2] = -lo16(th.y) * fast_tanh(lo16(q.y) + acc[2]);
    res[3] = -hi16(th.y) * fast_tanh(hi16(q.y) + acc[3]);
    res[4] = -lo16(th.z) * fast_tanh(lo16(q.z) + acc[4]);
    res[5] = -hi16(th.z) * fast_tanh(hi16(q.z) + acc[5]);
    res[6] = -lo16(th.w) * fast_tanh(lo16(q.w) + acc[6]);
    res[7] = -hi16(th.w) * fast_tanh(hi16(q.w) + acc[7]);
    int b = lane >> 3;
    int f0 = ((lane * 4) & 31) * 2;
    float* dst = outF + (size_t)b * (N_NODES * 64) + (size_t)n * 64 + f0;
    *(float4*)(dst) = make_float4(res[0], res[1], res[2], res[3]);
    *(float4*)(dst + 4) = make_float4(res[4], res[5], res[6], res[7]);
}

// ---------------- MFMA GEMM: 64 rows/block (4 waves x 16 rows), optional col-split ---
struct Slabs { const u16* p[5]; };

// MODE 0: plain (+bias1 on cols<64) -> 64-wide slabs at O1
// MODE 1: fused: col<64 sigmoid(+bias1)->O1 (64-wide); col>=64 tanh(+bias2)->O2 (128-wide)
template <int FIN, int NM, int NOUT, int NSPLIT, int MODE>
__global__ __launch_bounds__(256) void gemm_kernel(
    Slabs A, const u16* __restrict__ Bp, const float* __restrict__ bias1,
    const float* __restrict__ bias2, u16* __restrict__ O1, u16* __restrict__ O2) {
    constexpr int K = NM * FIN;
    constexpr int KS = K / 32;
    constexpr int CTT = NOUT / 16;
    constexpr int CT = CTT / NSPLIT;
    int lane = threadIdx.x & 63;
    int wave = threadIdx.x >> 6;
    int rowBase = (blockIdx.x / NSPLIT) * 64 + wave * 16;
    int ctBase = (blockIdx.x % NSPLIT) * CT;
    int mrow = lane & 15;
    int kq = lane >> 4;

    float4v acc[CT];
#pragma unroll
    for (int c = 0; c < CT; c++) acc[c] = (float4v){0.f, 0.f, 0.f, 0.f};

#pragma unroll
    for (int ks = 0; ks < KS; ks++) {
        int k = ks * 32 + kq * 8;
        int m = k / FIN;  // uniform within ks
        int koff = k % FIN;
        short8 a = *(const short8*)(A.p[m] + (size_t)(rowBase + mrow) * FIN + koff);
        short8 b[CT];
#pragma unroll
        for (int ct = 0; ct < CT; ct++)
            b[ct] = *(const short8*)(Bp + ((size_t)(ks * CTT + ctBase + ct) * 64 + lane) * 8);
#pragma unroll
        for (int ct = 0; ct < CT; ct++)
            acc[ct] = __builtin_amdgcn_mfma_f32_16x16x32_bf16(a, b[ct], acc[ct], 0, 0, 0);
    }

    int rowq = rowBase + kq * 4;
#pragma unroll
    for (int ct = 0; ct < CT; ct++) {
        int col = (ctBase + ct) * 16 + mrow;
        float bsv;
        if (MODE == 0) bsv = (col < 64) ? bias1[col] : 0.f;
        else bsv = (col < 64) ? bias1[col] : bias2[col - 64];
#pragma unroll
        for (int i = 0; i < 4; i++) {
            float v = acc[ct][i] + bsv;
            int r = rowq + i;
            if (MODE == 0) {
                O1[(size_t)(col >> 6) * SLAB + (size_t)r * 64 + (col & 63)] = f2bf(v);
            } else {
                if (col < 64) {
                    v = 1.f / (1.f + __expf(-v));
                    O1[(size_t)r * 64 + col] = f2bf(v);
                } else {
                    O2[(size_t)r * 128 + (col - 64)] = f2bf(fast_tanh(v));
                }
            }
        }
    }
}

// ---------------- launch ----------------
extern "C" void kernel_launch(void* const* d_in, const int* in_sizes, int n_in,
                              void* d_out, int out_size, void* d_ws, size_t ws_size,
                              hipStream_t stream) {
    const float2* y    = (const float2*)d_in[0];
    const float* W_lat = (const float*)d_in[1];
    const float* b_lat = (const float*)d_in[2];
    const float* W_units = (const float*)d_in[3];
    const float* b_units = (const float*)d_in[4];
    const float* W_final = (const float*)d_in[5];
    const float* sup1w = (const float*)d_in[6];
    const float* sup2w = (const float*)d_in[7];
    const int* rows    = (const int*)d_in[8];
    const int* cols    = (const int*)d_in[9];
    float* out = (float*)d_out;

    char* ws = (char*)d_ws;
    size_t off = 0;
    auto alloc = [&](size_t bytes) -> void* {
        void* p = ws + off;
        off += (bytes + 511) & ~(size_t)511;
        return p;
    };
    int* rowptr1 = (int*)alloc((N_NODES + 1) * 4);
    int* rowptr2 = (int*)alloc((N_NODES + 1) * 4);
    int* cnt = (int*)alloc((size_t)2 * N_NODES * 4);
    int* bsums = (int*)alloc(80 * 4);
    int2* edges1 = (int2*)alloc((size_t)NEDGE * 8);
    int2* edges2 = (int2*)alloc((size_t)NEDGE * 8);
    u16* bpk12 = (u16*)alloc((size_t)61440 * 2);
    u16* bpkP = (u16*)alloc((size_t)40960 * 2);
    u16* theta = (u16*)alloc((size_t)NB * 64 * 2);
    u16* S = (u16*)alloc((size_t)5 * NB * 64 * 2);  // X-slabs, later Q/P slabs
    u16* H0 = (u16*)alloc((size_t)NB * 128 * 2);
    u16* T1 = (u16*)alloc((size_t)NB * 64 * 2);
    u16* T2 = (u16*)alloc((size_t)NB * 64 * 2);

    hipMemsetAsync(cnt, 0, (size_t)2 * N_NODES * 4, stream);
    prepcount_kernel<<<11025, 256, 0, stream>>>(y, (u32*)S, W_lat, W_units, bpk12,
                                                W_final, bpkP, rows, cols, cnt);
    blocksum_kernel<<<80, 256, 0, stream>>>(cnt, bsums);
    scanapply_kernel<<<80, 256, 0, stream>>>(cnt, bsums, rowptr1, rowptr2);
    scatter_kernel<<<625, 256, 0, stream>>>(rows, cols, sup1w, sup2w,
                                            cnt, cnt + N_NODES, edges1, edges2);

    // x-side diffusion: X1 = S1@X0, X3 = S2@X0 ; X2 = 2*S1@X1 - X0, X4 = 2*S2@X3 - X0
    const u32* S0 = (const u32*)S;
    u32* X1 = (u32*)(S + 1 * SLAB);
    u32* X2 = (u32*)(S + 2 * SLAB);
    u32* X3 = (u32*)(S + 3 * SLAB);
    u32* X4 = (u32*)(S + 4 * SLAB);
    spmm2_kernel<<<5000, 256, 0, stream>>>(S0, nullptr, X1, S0, nullptr, X3,
                                           rowptr1, edges1, rowptr2, edges2, 1.f, 0.f);
    spmm2_kernel<<<5000, 256, 0, stream>>>(X1, S0, X2, X3, S0, X4,
                                           rowptr1, edges1, rowptr2, edges2, 2.f, -1.f);

    Slabs SX;
    for (int m = 0; m < 5; m++) SX.p[m] = S + (size_t)m * SLAB;
    // fused: theta = sigmoid(X@W_lat + b_lat), H0 = tanh(X@W_units + b_units)
    gemm_kernel<64, 5, 192, 1, 1><<<1250, 256, 0, stream>>>(SX, bpk12, b_lat, b_units, theta, H0);

    // P-GEMM: [Q|P1|P2|P3|P4] = H0 @ bpkP (Q = P0-P2-P4 + b_lat), overlays S
    Slabs SH;
    SH.p[0] = H0;
    gemm_kernel<128, 1, 320, 2, 0><<<2500, 256, 0, stream>>>(SH, bpkP, b_lat, nullptr, S, nullptr);

    const u32* Q  = (const u32*)(S + 0 * SLAB);
    const u32* P1 = (const u32*)(S + 1 * SLAB);
    const u32* P2 = (const u32*)(S + 2 * SLAB);
    const u32* P3 = (const u32*)(S + 3 * SLAB);
    const u32* P4 = (const u32*)(S + 4 * SLAB);
    // T1 = P1 + 2*S1@P2 ; T2 = P3 + 2*S2@P4
    spmm2_kernel<<<5000, 256, 0, stream>>>(P2, P1, (u32*)T1, P4, P3, (u32*)T2,
                                           rowptr1, edges1, rowptr2, edges2, 2.f, 1.f);
    // out = -theta * tanh(Q + S1@T1 + S2@T2)
    spmm_final_kernel<<<2500, 256, 0, stream>>>((const u32*)T1, (const u32*)T2, Q,
                                                (const u32*)theta,
                                                rowptr1, edges1, rowptr2, edges2, out);
}